// Round 2
// baseline (718.109 us; speedup 1.0000x reference)
//
#include <hip/hip_runtime.h>
#include <stdint.h>

#define DHID 64  // hidden dim, fixed by problem

static inline size_t align256(size_t x) { return (x + 255) & ~(size_t)255; }

// ---------------- CSR build ----------------

__global__ void zero_i32(int* __restrict__ p, int n) {
  int i = blockIdx.x * blockDim.x + threadIdx.x;
  if (i < n) p[i] = 0;
}

__global__ void zero_f32(float* __restrict__ p, size_t n) {
  size_t i = (size_t)blockIdx.x * blockDim.x + threadIdx.x;
  if (i < n) p[i] = 0.f;
}

__global__ void hist_k(const int* __restrict__ row, int* __restrict__ count, int nnz) {
  int e = blockIdx.x * blockDim.x + threadIdx.x;
  if (e < nnz) atomicAdd(&count[row[e]], 1);
}

// scan over n counts, chunked at 2048 elems/block (8 per thread, 256 threads)
__global__ void scan1_k(const int* __restrict__ count, int* __restrict__ bsum, int n) {
  __shared__ int lds[4];
  int base = blockIdx.x * 2048 + threadIdx.x * 8;
  int s = 0;
#pragma unroll
  for (int i = 0; i < 8; ++i) { int idx = base + i; if (idx < n) s += count[idx]; }
#pragma unroll
  for (int off = 32; off > 0; off >>= 1) s += __shfl_down(s, off);
  if ((threadIdx.x & 63) == 0) lds[threadIdx.x >> 6] = s;
  __syncthreads();
  if (threadIdx.x == 0) bsum[blockIdx.x] = lds[0] + lds[1] + lds[2] + lds[3];
}

// single wave: exclusive-scan the (<=64) block sums; write total to rowstart[n]/cursor[n]
__global__ void scan2_k(int* __restrict__ bsum, int nb, int* __restrict__ rowstart,
                        int* __restrict__ cursor, int n) {
  int lane = threadIdx.x;
  int v = (lane < nb) ? bsum[lane] : 0;
  int incl = v;
#pragma unroll
  for (int off = 1; off < 64; off <<= 1) {
    int t = __shfl_up(incl, off);
    if (lane >= off) incl += t;
  }
  if (lane < nb) bsum[lane] = incl - v;          // exclusive block offset
  if (lane == 63) { rowstart[n] = incl; cursor[n] = incl; }  // total = nnz
}

__global__ void scan3_k(const int* __restrict__ count, const int* __restrict__ bsum,
                        int* __restrict__ rowstart, int* __restrict__ cursor, int n) {
  __shared__ int wsum[4];
  int base = blockIdx.x * 2048 + threadIdx.x * 8;
  int vals[8];
  int s = 0;
#pragma unroll
  for (int i = 0; i < 8; ++i) { int idx = base + i; vals[i] = (idx < n) ? count[idx] : 0; s += vals[i]; }
  int lane = threadIdx.x & 63, wid = threadIdx.x >> 6;
  int incl = s;
#pragma unroll
  for (int off = 1; off < 64; off <<= 1) {
    int t = __shfl_up(incl, off);
    if (lane >= off) incl += t;
  }
  if (lane == 63) wsum[wid] = incl;
  __syncthreads();
  int run = bsum[blockIdx.x] + (incl - s);
  for (int w = 0; w < wid; ++w) run += wsum[w];
#pragma unroll
  for (int i = 0; i < 8; ++i) {
    int idx = base + i;
    if (idx < n) { rowstart[idx] = run; cursor[idx] = run; }
    run += vals[i];
  }
}

// packed 8B scatter: one scattered store per edge instead of two
__global__ void scatter_k(const int* __restrict__ row, const int* __restrict__ col,
                          const float* __restrict__ val, int* __restrict__ cursor,
                          int2* __restrict__ edges, int nnz) {
  int e = blockIdx.x * blockDim.x + threadIdx.x;
  if (e < nnz) {
    int pos = atomicAdd(&cursor[row[e]], 1);
    int2 p;
    p.x = col[e];
    p.y = __float_as_int(val[e]);
    edges[pos] = p;
  }
}

// ---------------- SpMM: one wave per row, lane = column ----------------
// start/end forced into SGPRs -> edge loads are wave-uniform s_load_dwordx2,
// x[] gathers are the only vector loads; 8 gathers in flight per wave.

__global__ void spmm_k(const int* __restrict__ rowstart, const int2* __restrict__ edges,
                       const float* __restrict__ x, float* __restrict__ y, int n) {
  int wave = (blockIdx.x * blockDim.x + threadIdx.x) >> 6;
  int lane = threadIdx.x & 63;
  if (wave >= n) return;
  int start = __builtin_amdgcn_readfirstlane(rowstart[wave]);
  int end   = __builtin_amdgcn_readfirstlane(rowstart[wave + 1]);
  float acc = 0.f;
  int k = start;
  for (; k + 8 <= end; k += 8) {
    int2 e0 = edges[k + 0], e1 = edges[k + 1], e2 = edges[k + 2], e3 = edges[k + 3];
    int2 e4 = edges[k + 4], e5 = edges[k + 5], e6 = edges[k + 6], e7 = edges[k + 7];
    float x0 = x[((size_t)e0.x << 6) + lane];
    float x1 = x[((size_t)e1.x << 6) + lane];
    float x2 = x[((size_t)e2.x << 6) + lane];
    float x3 = x[((size_t)e3.x << 6) + lane];
    float x4 = x[((size_t)e4.x << 6) + lane];
    float x5 = x[((size_t)e5.x << 6) + lane];
    float x6 = x[((size_t)e6.x << 6) + lane];
    float x7 = x[((size_t)e7.x << 6) + lane];
    acc += __int_as_float(e0.y) * x0;
    acc += __int_as_float(e1.y) * x1;
    acc += __int_as_float(e2.y) * x2;
    acc += __int_as_float(e3.y) * x3;
    acc += __int_as_float(e4.y) * x4;
    acc += __int_as_float(e5.y) * x5;
    acc += __int_as_float(e6.y) * x6;
    acc += __int_as_float(e7.y) * x7;
  }
  for (; k < end; ++k) {
    int2 e = edges[k];
    acc += __int_as_float(e.y) * x[((size_t)e.x << 6) + lane];
  }
  y[((size_t)wave << 6) + lane] = acc;
}

// layer-2 SpMM with fused epilogue: writes e2, summed = e0+e1+e2, and e0 copy.
__global__ void spmm_fused_k(const int* __restrict__ rowstart, const int2* __restrict__ edges,
                             const float* __restrict__ e0, const float* __restrict__ e1,
                             float* __restrict__ e2, float* __restrict__ summed,
                             float* __restrict__ e0out, int n) {
  int wave = (blockIdx.x * blockDim.x + threadIdx.x) >> 6;
  int lane = threadIdx.x & 63;
  if (wave >= n) return;
  int start = __builtin_amdgcn_readfirstlane(rowstart[wave]);
  int end   = __builtin_amdgcn_readfirstlane(rowstart[wave + 1]);
  float acc = 0.f;
  int k = start;
  for (; k + 8 <= end; k += 8) {
    int2 ea = edges[k + 0], eb = edges[k + 1], ec = edges[k + 2], ed = edges[k + 3];
    int2 ee = edges[k + 4], ef = edges[k + 5], eg = edges[k + 6], eh = edges[k + 7];
    float x0 = e1[((size_t)ea.x << 6) + lane];
    float x1 = e1[((size_t)eb.x << 6) + lane];
    float x2 = e1[((size_t)ec.x << 6) + lane];
    float x3 = e1[((size_t)ed.x << 6) + lane];
    float x4 = e1[((size_t)ee.x << 6) + lane];
    float x5 = e1[((size_t)ef.x << 6) + lane];
    float x6 = e1[((size_t)eg.x << 6) + lane];
    float x7 = e1[((size_t)eh.x << 6) + lane];
    acc += __int_as_float(ea.y) * x0;
    acc += __int_as_float(eb.y) * x1;
    acc += __int_as_float(ec.y) * x2;
    acc += __int_as_float(ed.y) * x3;
    acc += __int_as_float(ee.y) * x4;
    acc += __int_as_float(ef.y) * x5;
    acc += __int_as_float(eg.y) * x6;
    acc += __int_as_float(eh.y) * x7;
  }
  for (; k < end; ++k) {
    int2 e = edges[k];
    acc += __int_as_float(e.y) * e1[((size_t)e.x << 6) + lane];
  }
  size_t o = ((size_t)wave << 6) + lane;
  float v0 = e0[o];
  float v1 = e1[o];
  e2[o] = acc;
  summed[o] = v0 + v1 + acc;
  e0out[o] = v0;
}

// ---------------- fallback: atomic SpMM (if ws too small) ----------------

__global__ void spmm_atomic_k(const int* __restrict__ row, const int* __restrict__ col,
                              const float* __restrict__ val, const float* __restrict__ x,
                              float* __restrict__ y, int nnz) {
  int wave = (blockIdx.x * blockDim.x + threadIdx.x) >> 6;
  int lane = threadIdx.x & 63;
  if (wave >= nnz) return;
  int r = row[wave]; int c = col[wave]; float v = val[wave];
  atomicAdd(&y[(size_t)r * DHID + lane], v * x[(size_t)c * DHID + lane]);
}

__global__ void sum_k(const float4* __restrict__ e0, const float4* __restrict__ e1,
                      const float4* __restrict__ e2, float4* __restrict__ summed,
                      float4* __restrict__ e0out, int n4) {
  int i = blockIdx.x * blockDim.x + threadIdx.x;
  if (i < n4) {
    float4 a = e0[i], b = e1[i], c = e2[i];
    float4 s;
    s.x = a.x + b.x + c.x;
    s.y = a.y + b.y + c.y;
    s.z = a.z + b.z + c.z;
    s.w = a.w + b.w + c.w;
    summed[i] = s;
    e0out[i] = a;
  }
}

extern "C" void kernel_launch(void* const* d_in, const int* in_sizes, int n_in,
                              void* d_out, int out_size, void* d_ws, size_t ws_size,
                              hipStream_t stream) {
  const int*   row = (const int*)d_in[0];
  const int*   col = (const int*)d_in[1];
  const float* val = (const float*)d_in[2];
  const float* emb = (const float*)d_in[3];
  int nnz = in_sizes[0];
  int n   = in_sizes[3] / DHID;
  size_t ND = (size_t)n * DHID;

  float* out    = (float*)d_out;
  float* summed = out;
  float* e0o    = out + ND;
  float* e1     = out + 2 * ND;
  float* e2     = out + 3 * ND;

  int nb = (n + 2047) / 2048;

  // carve workspace
  size_t o0 = 0;
  size_t count_off    = o0; o0 += align256((size_t)(n + 1) * 4);
  size_t rowstart_off = o0; o0 += align256((size_t)(n + 1) * 4);
  size_t cursor_off   = o0; o0 += align256((size_t)(n + 1) * 4);
  size_t bsum_off     = o0; o0 += align256(256 * 4);
  size_t edges_off    = o0; o0 += align256((size_t)nnz * 8);
  size_t need = o0;

  bool use_csr = (ws_size >= need) && (nb <= 64);

  int eb = (nnz + 255) / 256;                       // edge-parallel blocks
  int wb = (int)(((size_t)nnz * 64 + 255) / 256);   // wave-per-edge blocks
  int rb = (int)((ND + 255) / 256);                 // wave-per-row blocks: n*64 threads
  int n4 = (int)(ND / 4);
  int sb = (n4 + 255) / 256;

  if (use_csr) {
    uint8_t* w = (uint8_t*)d_ws;
    int*   count    = (int*)(w + count_off);
    int*   rowstart = (int*)(w + rowstart_off);
    int*   cursor   = (int*)(w + cursor_off);
    int*   bsum     = (int*)(w + bsum_off);
    int2*  edges    = (int2*)(w + edges_off);

    zero_i32<<<(n + 255) / 256, 256, 0, stream>>>(count, n);
    hist_k<<<eb, 256, 0, stream>>>(row, count, nnz);
    scan1_k<<<nb, 256, 0, stream>>>(count, bsum, n);
    scan2_k<<<1, 64, 0, stream>>>(bsum, nb, rowstart, cursor, n);
    scan3_k<<<nb, 256, 0, stream>>>(count, bsum, rowstart, cursor, n);
    scatter_k<<<eb, 256, 0, stream>>>(row, col, val, cursor, edges, nnz);

    spmm_k<<<rb, 256, 0, stream>>>(rowstart, edges, emb, e1, n);
    spmm_fused_k<<<rb, 256, 0, stream>>>(rowstart, edges, emb, e1, e2, summed, e0o, n);
  } else {
    zero_f32<<<(int)((ND + 255) / 256), 256, 0, stream>>>(e1, ND);
    spmm_atomic_k<<<wb, 256, 0, stream>>>(row, col, val, emb, e1, nnz);
    zero_f32<<<(int)((ND + 255) / 256), 256, 0, stream>>>(e2, ND);
    spmm_atomic_k<<<wb, 256, 0, stream>>>(row, col, val, e1, e2, nnz);
    sum_k<<<sb, 256, 0, stream>>>((const float4*)emb, (const float4*)e1,
                                  (const float4*)e2, (float4*)summed,
                                  (float4*)e0o, n4);
  }
}

// Round 3
// 487.637 us; speedup vs baseline: 1.4726x; 1.4726x over previous
//
#include <hip/hip_runtime.h>
#include <stdint.h>

#define DHID 64      // hidden dim, fixed by problem
#define G_BLOCKS 256 // blocks in phase-A (must equal blockDim of scan_gb_k)
#define BMAX 512     // max buckets (n <= 131072)

static inline size_t align256(size_t x) { return (x + 255) & ~(size_t)255; }

// ---------------- generic helpers ----------------

__global__ void zero_i32(int* __restrict__ p, int n) {
  int i = blockIdx.x * blockDim.x + threadIdx.x;
  if (i < n) p[i] = 0;
}

__global__ void zero_f32(float* __restrict__ p, size_t n) {
  size_t i = (size_t)blockIdx.x * blockDim.x + threadIdx.x;
  if (i < n) p[i] = 0.f;
}

// ---------------- phase A: bucket partition (bucket = row >> 8) ----------------

// per-(block,bucket) histogram; LDS atomics only
__global__ void a1_hist_k(const int* __restrict__ row, int* __restrict__ histGB,
                          int nnz, int B, int chunk) {
  __shared__ int h[BMAX];
  for (int i = threadIdx.x; i < B; i += blockDim.x) h[i] = 0;
  __syncthreads();
  int g = blockIdx.x;
  int s = g * chunk, e = min(nnz, s + chunk);
  for (int j = s + threadIdx.x; j < e; j += blockDim.x)
    atomicAdd(&h[row[j] >> 8], 1);
  __syncthreads();
  for (int i = threadIdx.x; i < B; i += blockDim.x)
    histGB[i * G_BLOCKS + g] = h[i];
}

// exclusive scan across blocks within each bucket; one block per bucket
__global__ void scan_gb_k(const int* __restrict__ histGB, int* __restrict__ offGB,
                          int* __restrict__ btot, int B) {
  __shared__ int wsum[4];
  int b = blockIdx.x, t = threadIdx.x, lane = t & 63, w = t >> 6;
  int v = histGB[b * G_BLOCKS + t];
  int incl = v;
#pragma unroll
  for (int off = 1; off < 64; off <<= 1) {
    int u = __shfl_up(incl, off);
    if (lane >= off) incl += u;
  }
  if (lane == 63) wsum[w] = incl;
  __syncthreads();
  int woff = 0;
  for (int w2 = 0; w2 < w; ++w2) woff += wsum[w2];
  offGB[b * G_BLOCKS + t] = woff + incl - v;
  if (t == 0) btot[b] = wsum[0] + wsum[1] + wsum[2] + wsum[3];
}

// exclusive scan of bucket totals -> base[0..B], base[B] = nnz. one block, 256 thr.
__global__ void scan_b_k(const int* __restrict__ btot, int* __restrict__ base, int B) {
  __shared__ int wsum[4];
  int t = threadIdx.x, lane = t & 63, w = t >> 6;
  int i0 = 2 * t, i1 = 2 * t + 1;
  int v0 = (i0 < B) ? btot[i0] : 0;
  int v1 = (i1 < B) ? btot[i1] : 0;
  int ps = v0 + v1, incl = ps;
#pragma unroll
  for (int off = 1; off < 64; off <<= 1) {
    int u = __shfl_up(incl, off);
    if (lane >= off) incl += u;
  }
  if (lane == 63) wsum[w] = incl;
  __syncthreads();
  int woff = 0;
  for (int w2 = 0; w2 < w; ++w2) woff += wsum[w2];
  int ex = woff + incl - ps;
  if (i0 <= B) base[i0] = ex;
  if (i1 <= B) base[i1] = ex + v0;
}

// scatter edges into bucket regions; each block writes only its private quota
// window per bucket (base[b] + offGB[b][g] ...), so L2 merges lines. No global atomics.
// payload packs row-low-8 into bits 24..31 of the col word (col < 2^24).
__global__ void a2_scatter_k(const int* __restrict__ row, const int* __restrict__ col,
                             const float* __restrict__ val, const int* __restrict__ base,
                             const int* __restrict__ offGB, int2* __restrict__ stage,
                             int nnz, int B, int chunk) {
  __shared__ int cur[BMAX];
  int g = blockIdx.x;
  for (int i = threadIdx.x; i < B; i += blockDim.x)
    cur[i] = base[i] + offGB[i * G_BLOCKS + g];
  __syncthreads();
  int s = g * chunk, e = min(nnz, s + chunk);
  for (int j = s + threadIdx.x; j < e; j += blockDim.x) {
    int r = row[j];
    int b = r >> 8;
    int pos = atomicAdd(&cur[b], 1);   // LDS atomic
    int2 p;
    p.x = ((r & 255) << 24) | col[j];
    p.y = __float_as_int(val[j]);
    stage[pos] = p;
  }
}

// ---------------- phase B: within-bucket row grouping ----------------

// per-row counts, coalesced writes (replaces random-atomic hist_k)
__global__ void b1_hist_k(const int2* __restrict__ stage, const int* __restrict__ base,
                          int* __restrict__ count, int n) {
  __shared__ int h[256];
  int b = blockIdx.x, t = threadIdx.x;
  h[t] = 0;
  __syncthreads();
  int s = base[b], e = base[b + 1];
  for (int j = s + t; j < e; j += 256)
    atomicAdd(&h[((unsigned)stage[j].x) >> 24], 1);
  __syncthreads();
  int r = (b << 8) + t;
  if (r < n) count[r] = h[t];
}

// scatter bucket edges to final row-grouped positions; block's output window
// is contiguous & exclusively owned -> full-line writebacks.
__global__ void b2_scatter_k(const int2* __restrict__ stage, const int* __restrict__ base,
                             const int* __restrict__ rowstart, int2* __restrict__ edges,
                             int n) {
  __shared__ int cur[256];
  int b = blockIdx.x, t = threadIdx.x;
  int r = (b << 8) + t;
  cur[t] = (r < n) ? rowstart[r] : 0;
  __syncthreads();
  int s = base[b], e = base[b + 1];
  for (int j = s + t; j < e; j += 256) {
    int2 p = stage[j];
    int rlow = ((unsigned)p.x) >> 24;
    int pos = atomicAdd(&cur[rlow], 1);  // LDS atomic
    int2 q;
    q.x = p.x & 0xFFFFFF;
    q.y = p.y;
    edges[pos] = q;
  }
}

// ---------------- row scan (count -> rowstart), n up to 64*2048 ----------------

__global__ void scan1_k(const int* __restrict__ count, int* __restrict__ bsum, int n) {
  __shared__ int lds[4];
  int base = blockIdx.x * 2048 + threadIdx.x * 8;
  int s = 0;
#pragma unroll
  for (int i = 0; i < 8; ++i) { int idx = base + i; if (idx < n) s += count[idx]; }
#pragma unroll
  for (int off = 32; off > 0; off >>= 1) s += __shfl_down(s, off);
  if ((threadIdx.x & 63) == 0) lds[threadIdx.x >> 6] = s;
  __syncthreads();
  if (threadIdx.x == 0) bsum[blockIdx.x] = lds[0] + lds[1] + lds[2] + lds[3];
}

__global__ void scan2_k(int* __restrict__ bsum, int nb, int* __restrict__ rowstart, int n) {
  int lane = threadIdx.x;
  int v = (lane < nb) ? bsum[lane] : 0;
  int incl = v;
#pragma unroll
  for (int off = 1; off < 64; off <<= 1) {
    int t = __shfl_up(incl, off);
    if (lane >= off) incl += t;
  }
  if (lane < nb) bsum[lane] = incl - v;
  if (lane == 63) rowstart[n] = incl;
}

__global__ void scan3_k(const int* __restrict__ count, const int* __restrict__ bsum,
                        int* __restrict__ rowstart, int n) {
  __shared__ int wsum[4];
  int base = blockIdx.x * 2048 + threadIdx.x * 8;
  int vals[8];
  int s = 0;
#pragma unroll
  for (int i = 0; i < 8; ++i) { int idx = base + i; vals[i] = (idx < n) ? count[idx] : 0; s += vals[i]; }
  int lane = threadIdx.x & 63, wid = threadIdx.x >> 6;
  int incl = s;
#pragma unroll
  for (int off = 1; off < 64; off <<= 1) {
    int t = __shfl_up(incl, off);
    if (lane >= off) incl += t;
  }
  if (lane == 63) wsum[wid] = incl;
  __syncthreads();
  int run = bsum[blockIdx.x] + (incl - s);
  for (int w = 0; w < wid; ++w) run += wsum[w];
#pragma unroll
  for (int i = 0; i < 8; ++i) {
    int idx = base + i;
    if (idx < n) rowstart[idx] = run;
    run += vals[i];
  }
}

// ---------------- SpMM: one wave per row ----------------

__global__ void spmm_k(const int* __restrict__ rowstart, const int2* __restrict__ edges,
                       const float* __restrict__ x, float* __restrict__ y, int n) {
  int wave = (blockIdx.x * blockDim.x + threadIdx.x) >> 6;
  int lane = threadIdx.x & 63;
  if (wave >= n) return;
  int start = __builtin_amdgcn_readfirstlane(rowstart[wave]);
  int end   = __builtin_amdgcn_readfirstlane(rowstart[wave + 1]);
  float acc = 0.f;
  int k = start;
  for (; k + 8 <= end; k += 8) {
    int2 e0 = edges[k + 0], e1 = edges[k + 1], e2 = edges[k + 2], e3 = edges[k + 3];
    int2 e4 = edges[k + 4], e5 = edges[k + 5], e6 = edges[k + 6], e7 = edges[k + 7];
    float x0 = x[((size_t)e0.x << 6) + lane];
    float x1 = x[((size_t)e1.x << 6) + lane];
    float x2 = x[((size_t)e2.x << 6) + lane];
    float x3 = x[((size_t)e3.x << 6) + lane];
    float x4 = x[((size_t)e4.x << 6) + lane];
    float x5 = x[((size_t)e5.x << 6) + lane];
    float x6 = x[((size_t)e6.x << 6) + lane];
    float x7 = x[((size_t)e7.x << 6) + lane];
    acc += __int_as_float(e0.y) * x0;
    acc += __int_as_float(e1.y) * x1;
    acc += __int_as_float(e2.y) * x2;
    acc += __int_as_float(e3.y) * x3;
    acc += __int_as_float(e4.y) * x4;
    acc += __int_as_float(e5.y) * x5;
    acc += __int_as_float(e6.y) * x6;
    acc += __int_as_float(e7.y) * x7;
  }
  for (; k < end; ++k) {
    int2 e = edges[k];
    acc += __int_as_float(e.y) * x[((size_t)e.x << 6) + lane];
  }
  y[((size_t)wave << 6) + lane] = acc;
}

__global__ void spmm_fused_k(const int* __restrict__ rowstart, const int2* __restrict__ edges,
                             const float* __restrict__ e0, const float* __restrict__ e1,
                             float* __restrict__ e2, float* __restrict__ summed,
                             float* __restrict__ e0out, int n) {
  int wave = (blockIdx.x * blockDim.x + threadIdx.x) >> 6;
  int lane = threadIdx.x & 63;
  if (wave >= n) return;
  int start = __builtin_amdgcn_readfirstlane(rowstart[wave]);
  int end   = __builtin_amdgcn_readfirstlane(rowstart[wave + 1]);
  float acc = 0.f;
  int k = start;
  for (; k + 8 <= end; k += 8) {
    int2 ea = edges[k + 0], eb = edges[k + 1], ec = edges[k + 2], ed = edges[k + 3];
    int2 ee = edges[k + 4], ef = edges[k + 5], eg = edges[k + 6], eh = edges[k + 7];
    float x0 = e1[((size_t)ea.x << 6) + lane];
    float x1 = e1[((size_t)eb.x << 6) + lane];
    float x2 = e1[((size_t)ec.x << 6) + lane];
    float x3 = e1[((size_t)ed.x << 6) + lane];
    float x4 = e1[((size_t)ee.x << 6) + lane];
    float x5 = e1[((size_t)ef.x << 6) + lane];
    float x6 = e1[((size_t)eg.x << 6) + lane];
    float x7 = e1[((size_t)eh.x << 6) + lane];
    acc += __int_as_float(ea.y) * x0;
    acc += __int_as_float(eb.y) * x1;
    acc += __int_as_float(ec.y) * x2;
    acc += __int_as_float(ed.y) * x3;
    acc += __int_as_float(ee.y) * x4;
    acc += __int_as_float(ef.y) * x5;
    acc += __int_as_float(eg.y) * x6;
    acc += __int_as_float(eh.y) * x7;
  }
  for (; k < end; ++k) {
    int2 e = edges[k];
    acc += __int_as_float(e.y) * e1[((size_t)e.x << 6) + lane];
  }
  size_t o = ((size_t)wave << 6) + lane;
  float v0 = e0[o];
  float v1 = e1[o];
  e2[o] = acc;
  summed[o] = v0 + v1 + acc;
  e0out[o] = v0;
}

// ---------------- fallback: atomic path ----------------

__global__ void spmm_atomic_k(const int* __restrict__ row, const int* __restrict__ col,
                              const float* __restrict__ val, const float* __restrict__ x,
                              float* __restrict__ y, int nnz) {
  int wave = (blockIdx.x * blockDim.x + threadIdx.x) >> 6;
  int lane = threadIdx.x & 63;
  if (wave >= nnz) return;
  int r = row[wave]; int c = col[wave]; float v = val[wave];
  atomicAdd(&y[(size_t)r * DHID + lane], v * x[(size_t)c * DHID + lane]);
}

__global__ void sum_k(const float4* __restrict__ e0, const float4* __restrict__ e1,
                      const float4* __restrict__ e2, float4* __restrict__ summed,
                      float4* __restrict__ e0out, int n4) {
  int i = blockIdx.x * blockDim.x + threadIdx.x;
  if (i < n4) {
    float4 a = e0[i], b = e1[i], c = e2[i];
    float4 s;
    s.x = a.x + b.x + c.x;
    s.y = a.y + b.y + c.y;
    s.z = a.z + b.z + c.z;
    s.w = a.w + b.w + c.w;
    summed[i] = s;
    e0out[i] = a;
  }
}

extern "C" void kernel_launch(void* const* d_in, const int* in_sizes, int n_in,
                              void* d_out, int out_size, void* d_ws, size_t ws_size,
                              hipStream_t stream) {
  const int*   row = (const int*)d_in[0];
  const int*   col = (const int*)d_in[1];
  const float* val = (const float*)d_in[2];
  const float* emb = (const float*)d_in[3];
  int nnz = in_sizes[0];
  int n   = in_sizes[3] / DHID;
  size_t ND = (size_t)n * DHID;

  float* out    = (float*)d_out;
  float* summed = out;
  float* e0o    = out + ND;
  float* e1     = out + 2 * ND;
  float* e2     = out + 3 * ND;

  int B  = (n + 255) >> 8;          // buckets of 256 rows
  int nb = (n + 2047) / 2048;       // row-scan blocks
  int chunk = (nnz + G_BLOCKS - 1) / G_BLOCKS;

  // carve workspace
  size_t o0 = 0;
  size_t count_off    = o0; o0 += align256((size_t)(n + 1) * 4);
  size_t rowstart_off = o0; o0 += align256((size_t)(n + 1) * 4);
  size_t bsum_off     = o0; o0 += align256(256 * 4);
  size_t histGB_off   = o0; o0 += align256((size_t)BMAX * G_BLOCKS * 4);
  size_t offGB_off    = o0; o0 += align256((size_t)BMAX * G_BLOCKS * 4);
  size_t btot_off     = o0; o0 += align256((size_t)BMAX * 4);
  size_t base_off     = o0; o0 += align256((size_t)(BMAX + 1) * 4);
  size_t stage_off    = o0; o0 += align256((size_t)nnz * 8);
  size_t edges_off    = o0; o0 += align256((size_t)nnz * 8);
  size_t need_sorted = o0;

  bool use_sorted = (ws_size >= need_sorted) && (B <= BMAX) && (nb <= 64) &&
                    (n < (1 << 24));

  int rb = (int)((ND + 255) / 256);   // wave-per-row: n*64 threads
  int n4 = (int)(ND / 4);
  int sb = (n4 + 255) / 256;
  int wb = (int)(((size_t)nnz * 64 + 255) / 256);

  if (use_sorted) {
    uint8_t* w = (uint8_t*)d_ws;
    int*  count    = (int*)(w + count_off);
    int*  rowstart = (int*)(w + rowstart_off);
    int*  bsum     = (int*)(w + bsum_off);
    int*  histGB   = (int*)(w + histGB_off);
    int*  offGB    = (int*)(w + offGB_off);
    int*  btot     = (int*)(w + btot_off);
    int*  base     = (int*)(w + base_off);
    int2* stage    = (int2*)(w + stage_off);
    int2* edges    = (int2*)(w + edges_off);

    // phase A: partition into 256-row buckets, zero global atomics
    a1_hist_k<<<G_BLOCKS, 256, 0, stream>>>(row, histGB, nnz, B, chunk);
    scan_gb_k<<<B, 256, 0, stream>>>(histGB, offGB, btot, B);
    scan_b_k<<<1, 256, 0, stream>>>(btot, base, B);
    a2_scatter_k<<<G_BLOCKS, 256, 0, stream>>>(row, col, val, base, offGB, stage,
                                               nnz, B, chunk);
    // phase B: group by row within each bucket
    b1_hist_k<<<B, 256, 0, stream>>>(stage, base, count, n);
    scan1_k<<<nb, 256, 0, stream>>>(count, bsum, n);
    scan2_k<<<1, 64, 0, stream>>>(bsum, nb, rowstart, n);
    scan3_k<<<nb, 256, 0, stream>>>(count, bsum, rowstart, n);
    b2_scatter_k<<<B, 256, 0, stream>>>(stage, base, rowstart, edges, n);

    // SpMM x2 (layer 2 fuses the e0+e1+e2 epilogue)
    spmm_k<<<rb, 256, 0, stream>>>(rowstart, edges, emb, e1, n);
    spmm_fused_k<<<rb, 256, 0, stream>>>(rowstart, edges, emb, e1, e2, summed, e0o, n);
  } else {
    zero_f32<<<(int)((ND + 255) / 256), 256, 0, stream>>>(e1, ND);
    spmm_atomic_k<<<wb, 256, 0, stream>>>(row, col, val, emb, e1, nnz);
    zero_f32<<<(int)((ND + 255) / 256), 256, 0, stream>>>(e2, ND);
    spmm_atomic_k<<<wb, 256, 0, stream>>>(row, col, val, e1, e2, nnz);
    sum_k<<<sb, 256, 0, stream>>>((const float4*)emb, (const float4*)e1,
                                  (const float4*)e2, (float4*)summed,
                                  (float4*)e0o, n4);
  }
}